// Round 3
// baseline (3387.294 us; speedup 1.0000x reference)
//
#include <hip/hip_runtime.h>

#define HDIM 256
#define KSTEPS 30
#define RPB 32            // rows per block
#define NTHR 512          // 8 waves

typedef _Float16 f16x8 __attribute__((ext_vector_type(8)));
typedef float f32x4 __attribute__((ext_vector_type(4)));

__device__ __forceinline__ f32x4 mfma16(f16x8 a, f16x8 b, f32x4 c) {
  return __builtin_amdgcn_mfma_f32_16x16x32_f16(a, b, c, 0, 0, 0);
}

__device__ __forceinline__ float sigm(float x) { return 1.0f / (1.0f + expf(-x)); }
__device__ __forceinline__ float softplusf(float x) {
  return fmaxf(x, 0.0f) + log1pf(expf(-fabsf(x)));
}

// swizzled byte offset for a [32][256] fp16 LDS tile (row stride 512B)
__device__ __forceinline__ int swz(int r, int c) {
  return r * 512 + ((c * 2) ^ ((r & 7) << 4));
}

__device__ __forceinline__ void wrsplit(char* hi, char* lo, int off, float v) {
  _Float16 h = (_Float16)v;
  *(_Float16*)(hi + off) = h;
  *(_Float16*)(lo + off) = (_Float16)(v - (float)h);
}
__device__ __forceinline__ float rdpair(const char* hi, const char* lo, int off) {
  return (float)*(const _Float16*)(hi + off) + (float)*(const _Float16*)(lo + off);
}

// ---------------- prep: f32->fp16 (hi/lo) conversions + teW ----------------
__global__ __launch_bounds__(256) void prep_kernel(
    const float* __restrict__ W1, const float* __restrict__ W2,
    const float* __restrict__ Wih0, const float* __restrict__ Whh0,
    const float* __restrict__ Wih1, const float* __restrict__ Whh1,
    const float* __restrict__ hf,
    _Float16* __restrict__ Whh0h, _Float16* __restrict__ Wih1h,
    _Float16* __restrict__ Whh1h,
    _Float16* __restrict__ W1h, _Float16* __restrict__ W1l,
    _Float16* __restrict__ W2h, _Float16* __restrict__ W2l,
    _Float16* __restrict__ Wih0hh, _Float16* __restrict__ Wih0hl,
    _Float16* __restrict__ hfh, _Float16* __restrict__ hfl,
    float* __restrict__ teW, int B)
{
  int e = blockIdx.x * 256 + threadIdx.x;
  if (e < 196608) { Whh0h[e] = (_Float16)Whh0[e]; return; } e -= 196608;
  if (e < 196608) { Wih1h[e] = (_Float16)Wih1[e]; return; } e -= 196608;
  if (e < 196608) { Whh1h[e] = (_Float16)Whh1[e]; return; } e -= 196608;
  if (e < 65536)  { float x = W1[e]; _Float16 h = (_Float16)x; W1h[e] = h; W1l[e] = (_Float16)(x - (float)h); return; } e -= 65536;
  if (e < 131072) { float x = W2[e]; _Float16 h = (_Float16)x; W2h[e] = h; W2l[e] = (_Float16)(x - (float)h); return; } e -= 131072;
  if (e < 196608) { int n = e >> 8, c = e & 255; float x = Wih0[n*291 + 35 + c]; _Float16 h = (_Float16)x; Wih0hh[e] = h; Wih0hl[e] = (_Float16)(x - (float)h); return; } e -= 196608;
  if (e < B*HDIM) { float x = hf[e]; _Float16 h = (_Float16)x; hfh[e] = h; hfl[e] = (_Float16)(x - (float)h); return; } e -= B*HDIM;
  if (e < KSTEPS*768) {
    int k = e / 768, n = e % 768;
    float pos = (float)k;
    const float fac = -9.210340371976184f / 31.0f;   // -ln(10000)/(TD-1)
    float acc = 0.0f;
    #pragma unroll
    for (int j = 0; j < 31; ++j) {
      int i = j >> 1;
      float ang = pos * expf((float)(2*i) * fac);
      float t = (j & 1) ? cosf(ang) : sinf(ang);
      acc += t * Wih0[n*291 + 3 + j];
    }
    acc += (pos / 30.0f) * Wih0[n*291 + 3 + 31];
    teW[e] = acc;
  }
}

// ------- XcT[n*B + r] = (hf @ Wih0[:,35:291].T)[r,n] + bih0[n]  (transposed, f32) -------
__global__ __launch_bounds__(64) void xc_kernel(
    const _Float16* __restrict__ hfh, const _Float16* __restrict__ hfl,
    const _Float16* __restrict__ Wh, const _Float16* __restrict__ Wl,
    const float* __restrict__ bih0, float* __restrict__ XcT, int B)
{
  int l = threadIdx.x, l15 = l & 15, l4 = l >> 4;
  int bm = blockIdx.x;   // rows bm*16
  int bn = blockIdx.y;   // cols bn*64
  f32x4 acc[4];
  #pragma unroll
  for (int i = 0; i < 4; ++i) acc[i] = (f32x4){0,0,0,0};
  const _Float16* ah = hfh + (size_t)(bm*16 + l15)*256 + l4*8;
  const _Float16* al = hfl + (size_t)(bm*16 + l15)*256 + l4*8;
  #pragma unroll
  for (int kk = 0; kk < 8; ++kk) {
    f16x8 aH = *(const f16x8*)(ah + kk*32);
    f16x8 aL = *(const f16x8*)(al + kk*32);
    #pragma unroll
    for (int i = 0; i < 4; ++i) {
      size_t boff = (size_t)(bn*64 + i*16 + l15)*256 + l4*8 + kk*32;
      f16x8 bH = *(const f16x8*)(Wh + boff);
      f16x8 bL = *(const f16x8*)(Wl + boff);
      acc[i] = mfma16(aH, bH, acc[i]);
      acc[i] = mfma16(aL, bH, acc[i]);
      acc[i] = mfma16(aH, bL, acc[i]);
    }
  }
  #pragma unroll
  for (int i = 0; i < 4; ++i) {
    int n = bn*64 + i*16 + l15;
    float bb = bih0[n];
    #pragma unroll
    for (int j = 0; j < 4; ++j) {
      int r = bm*16 + l4*4 + j;
      XcT[(size_t)n*B + r] = acc[i][j] + bb;
    }
  }
}

// ---------------- main persistent GRU kernel ----------------
// LDS layout (bytes): h tiles are [32][256] fp16 swizzled, 16KB each
#define OFF_H0    0        // buf b: hi @ b*32768, lo @ b*32768+16384
#define OFF_H1    65536    // same structure
#define OFF_WS3   131072   // 768*3 f32 (Wih0[:,0:3])
#define OFF_BHH0  140288   // 768 f32
#define OFF_BI1   143360
#define OFF_BH1   146432
#define OFF_WOUT  149504
#define OFF_SPH   152576   // 32*8 f32
#define OFF_BOUT  153600
#define LDS_BYTES 153616

__global__ __launch_bounds__(NTHR, 2) void gru_main(
    const float* __restrict__ istate,
    const float* __restrict__ b1g, const float* __restrict__ b2g,
    const float* __restrict__ Wih0, const float* __restrict__ bhh0g,
    const float* __restrict__ bih1g, const float* __restrict__ bhh1g,
    const float* __restrict__ Woutg, const float* __restrict__ boutg,
    const _Float16* __restrict__ Whh0h, const _Float16* __restrict__ Wih1h,
    const _Float16* __restrict__ Whh1h,
    const _Float16* __restrict__ W1h, const _Float16* __restrict__ W1l,
    const _Float16* __restrict__ W2h, const _Float16* __restrict__ W2l,
    const _Float16* __restrict__ hfh, const _Float16* __restrict__ hfl,
    const float* __restrict__ teW, const float* __restrict__ XcT,
    float* __restrict__ out, int B)
{
  extern __shared__ char smem[];
  float* Ws3   = (float*)(smem + OFF_WS3);
  float* bhh0L = (float*)(smem + OFF_BHH0);
  float* bi1L  = (float*)(smem + OFF_BI1);
  float* bh1L  = (float*)(smem + OFF_BH1);
  float* WoutL = (float*)(smem + OFF_WOUT);
  float* sph   = (float*)(smem + OFF_SPH);
  float* boutL = (float*)(smem + OFF_BOUT);

  const int tid = threadIdx.x;
  const int w = tid >> 6;
  const int lane = tid & 63;
  const int l15 = lane & 15;
  const int l4 = lane >> 4;
  const int row0 = blockIdx.x * RPB;

  // ---- constants to LDS
  for (int i = tid; i < 2304; i += NTHR) Ws3[i] = Wih0[(i/3)*291 + (i%3)];
  for (int i = tid; i < 768; i += NTHR) {
    bhh0L[i] = bhh0g[i]; bi1L[i] = bih1g[i]; bh1L[i] = bhh1g[i]; WoutL[i] = Woutg[i];
  }
  if (tid < 3) boutL[tid] = boutg[tid];
  if (tid < RPB) {
    const float* is = istate + (size_t)(row0 + tid) * 3;
    float s0 = is[0], s1 = is[1], s2 = is[2];
    float* sp = sph + tid*8;
    sp[0] = s0; sp[1] = s1; sp[2] = s2;
    sp[3] = s0; sp[4] = s0; sp[5] = s0;   // pos_hist = initial_state[:,0] x3
  }

  // ---- h_init GEMM1: relu(hf @ W1.T + b1) -> hmid in h1-buf1 (hi/lo), 3-pass split
  {
    char* mH = smem + OFF_H1 + 32768;
    char* mL = smem + OFF_H1 + 49152;
    #pragma unroll
    for (int i = 0; i < 2; ++i) {
      int nt = w*2 + i;
      f32x4 acc0 = {0,0,0,0}, acc1 = {0,0,0,0};
      const _Float16* brh = W1h + (nt*16 + l15)*256 + l4*8;
      const _Float16* brl = W1l + (nt*16 + l15)*256 + l4*8;
      const _Float16* a0h = hfh + (size_t)(row0 + l15)*256 + l4*8;
      const _Float16* a0l = hfl + (size_t)(row0 + l15)*256 + l4*8;
      #pragma unroll
      for (int kk = 0; kk < 8; ++kk) {
        f16x8 bH = *(const f16x8*)(brh + kk*32);
        f16x8 bL = *(const f16x8*)(brl + kk*32);
        f16x8 aH0 = *(const f16x8*)(a0h + kk*32);
        f16x8 aL0 = *(const f16x8*)(a0l + kk*32);
        f16x8 aH1 = *(const f16x8*)(a0h + 16*256 + kk*32);
        f16x8 aL1 = *(const f16x8*)(a0l + 16*256 + kk*32);
        acc0 = mfma16(aH0, bH, acc0); acc0 = mfma16(aL0, bH, acc0); acc0 = mfma16(aH0, bL, acc0);
        acc1 = mfma16(aH1, bH, acc1); acc1 = mfma16(aL1, bH, acc1); acc1 = mfma16(aH1, bL, acc1);
      }
      int n = nt*16 + l15;
      float bb = b1g[n];
      #pragma unroll
      for (int mt = 0; mt < 2; ++mt) {
        f32x4 acc = mt ? acc1 : acc0;
        #pragma unroll
        for (int j = 0; j < 4; ++j) {
          int r = mt*16 + l4*4 + j;
          float v = fmaxf(acc[j] + bb, 0.0f);
          wrsplit(mH, mL, swz(r, n), v);
        }
      }
    }
  }
  __syncthreads();

  // ---- h_init GEMM2: tanh(hmid @ W2.T + b2) -> h0 buf0 / h1 buf0 (hi/lo)
  {
    const char* mH = smem + OFF_H1 + 32768;
    const char* mL = smem + OFF_H1 + 49152;
    char* o0H = smem + OFF_H0;          char* o0L = smem + OFF_H0 + 16384;
    char* o1H = smem + OFF_H1;          char* o1L = smem + OFF_H1 + 16384;
    #pragma unroll
    for (int i = 0; i < 4; ++i) {
      int nt = w*4 + i;
      f32x4 acc0 = {0,0,0,0}, acc1 = {0,0,0,0};
      const _Float16* brh = W2h + (nt*16 + l15)*256 + l4*8;
      const _Float16* brl = W2l + (nt*16 + l15)*256 + l4*8;
      #pragma unroll
      for (int kk = 0; kk < 8; ++kk) {
        int kc = kk*32 + l4*8;
        f16x8 bH = *(const f16x8*)(brh + kk*32);
        f16x8 bL = *(const f16x8*)(brl + kk*32);
        f16x8 aH0 = *(const f16x8*)(mH + swz(l15, kc));
        f16x8 aL0 = *(const f16x8*)(mL + swz(l15, kc));
        f16x8 aH1 = *(const f16x8*)(mH + swz(16 + l15, kc));
        f16x8 aL1 = *(const f16x8*)(mL + swz(16 + l15, kc));
        acc0 = mfma16(aH0, bH, acc0); acc0 = mfma16(aL0, bH, acc0); acc0 = mfma16(aH0, bL, acc0);
        acc1 = mfma16(aH1, bH, acc1); acc1 = mfma16(aL1, bH, acc1); acc1 = mfma16(aH1, bL, acc1);
      }
      int n = nt*16 + l15;
      float bb = b2g[n];
      #pragma unroll
      for (int mt = 0; mt < 2; ++mt) {
        f32x4 acc = mt ? acc1 : acc0;
        #pragma unroll
        for (int j = 0; j < 4; ++j) {
          int r = mt*16 + l4*4 + j;
          float v = tanhf(acc[j] + bb);
          if (n < 256) wrsplit(o0H, o0L, swz(r, n), v);
          else         wrsplit(o1H, o1L, swz(r, n - 256), v);
        }
      }
    }
  }
  __syncthreads();

  const size_t outP = (size_t)B * KSTEPS;

  for (int k = 0; k < KSTEPS; ++k) {
    const int rb = (k & 1) * 32768, wb = ((k & 1) ^ 1) * 32768;
    const char* h0RH = smem + OFF_H0 + rb; const char* h0RL = h0RH + 16384;
    char*       h0WH = smem + OFF_H0 + wb; char*       h0WL = h0WH + 16384;
    const char* h1RH = smem + OFF_H1 + rb; const char* h1RL = h1RH + 16384;
    char*       h1WH = smem + OFF_H1 + wb; char*       h1WL = h1WH + 16384;
    const float* teWk = teW + k*768;

    // ---- Phase B: gh0 = h0 @ Whh0.T (pipelined), fused GRU-0 epilogue -> h0W
    #pragma unroll
    for (int hti = 0; hti < 2; ++hti) {
      int ht = w + hti*8;
      int h = ht*16 + l15;
      // hoisted epilogue loads (hide under K-loop)
      float teR = teWk[h], teZ = teWk[256 + h], teN = teWk[512 + h];
      f32x4 xcR[2], xcZ[2], xcN[2];
      #pragma unroll
      for (int mt = 0; mt < 2; ++mt) {
        size_t base = (size_t)row0 + mt*16 + l4*4;
        xcR[mt] = *(const f32x4*)(XcT + (size_t)h*B + base);
        xcZ[mt] = *(const f32x4*)(XcT + (size_t)(256 + h)*B + base);
        xcN[mt] = *(const f32x4*)(XcT + (size_t)(512 + h)*B + base);
      }
      const _Float16* br = Whh0h + (ht*16 + l15)*256 + l4*8;
      f16x8 wR = *(const f16x8*)(br);
      f16x8 wZ = *(const f16x8*)(br + 65536);
      f16x8 wN = *(const f16x8*)(br + 131072);
      f32x4 c[3][2];
      #pragma unroll
      for (int g = 0; g < 3; ++g) { c[g][0] = (f32x4){0,0,0,0}; c[g][1] = (f32x4){0,0,0,0}; }
      #pragma unroll
      for (int kk = 0; kk < 8; ++kk) {
        f16x8 nR, nZ, nN;
        if (kk < 7) {
          nR = *(const f16x8*)(br + (kk+1)*32);
          nZ = *(const f16x8*)(br + 65536 + (kk+1)*32);
          nN = *(const f16x8*)(br + 131072 + (kk+1)*32);
        }
        int kc = kk*32 + l4*8;
        f16x8 aH0 = *(const f16x8*)(h0RH + swz(l15, kc));
        f16x8 aL0 = *(const f16x8*)(h0RL + swz(l15, kc));
        f16x8 aH1 = *(const f16x8*)(h0RH + swz(16 + l15, kc));
        f16x8 aL1 = *(const f16x8*)(h0RL + swz(16 + l15, kc));
        c[0][0] = mfma16(aH0, wR, c[0][0]); c[0][0] = mfma16(aL0, wR, c[0][0]);
        c[0][1] = mfma16(aH1, wR, c[0][1]); c[0][1] = mfma16(aL1, wR, c[0][1]);
        c[1][0] = mfma16(aH0, wZ, c[1][0]); c[1][0] = mfma16(aL0, wZ, c[1][0]);
        c[1][1] = mfma16(aH1, wZ, c[1][1]); c[1][1] = mfma16(aL1, wZ, c[1][1]);
        c[2][0] = mfma16(aH0, wN, c[2][0]); c[2][0] = mfma16(aL0, wN, c[2][0]);
        c[2][1] = mfma16(aH1, wN, c[2][1]); c[2][1] = mfma16(aL1, wN, c[2][1]);
        if (kk < 7) { wR = nR; wZ = nZ; wN = nN; }
      }
      float wR0 = Ws3[h*3+0],       wR1 = Ws3[h*3+1],       wR2 = Ws3[h*3+2];
      float wZ0 = Ws3[(h+256)*3+0], wZ1 = Ws3[(h+256)*3+1], wZ2 = Ws3[(h+256)*3+2];
      float wN0 = Ws3[(h+512)*3+0], wN1 = Ws3[(h+512)*3+1], wN2 = Ws3[(h+512)*3+2];
      float bhR = bhh0L[h], bhZ = bhh0L[256 + h], bhN = bhh0L[512 + h];
      #pragma unroll
      for (int mt = 0; mt < 2; ++mt) {
        #pragma unroll
        for (int j = 0; j < 4; ++j) {
          int r = mt*16 + l4*4 + j;
          const float* sp = sph + r*8;
          float s0 = sp[0], s1 = sp[1], s2 = sp[2];
          float giR = xcR[mt][j] + teR + s0*wR0 + s1*wR1 + s2*wR2;
          float giZ = xcZ[mt][j] + teZ + s0*wZ0 + s1*wZ1 + s2*wZ2;
          float giN = xcN[mt][j] + teN + s0*wN0 + s1*wN1 + s2*wN2;
          float rg = sigm(giR + c[0][mt][j] + bhR);
          float zg = sigm(giZ + c[1][mt][j] + bhZ);
          float ng = tanhf(giN + rg * (c[2][mt][j] + bhN));
          float hold = rdpair(h0RH, h0RL, swz(r, h));
          float hnew = (1.0f - zg) * ng + zg * hold;
          wrsplit(h0WH, h0WL, swz(r, h), hnew);
        }
      }
    }
    __syncthreads();

    // ---- Phase AC (fused): gh1 = h1 @ Whh1.T AND gi1 = h0n @ Wih1.T, GRU-1 epilogue -> h1W
    #pragma unroll
    for (int hti = 0; hti < 2; ++hti) {
      int ht = w + hti*8;
      const _Float16* bh = Whh1h + (ht*16 + l15)*256 + l4*8;
      const _Float16* bi = Wih1h + (ht*16 + l15)*256 + l4*8;
      f16x8 whR = *(const f16x8*)(bh);
      f16x8 whZ = *(const f16x8*)(bh + 65536);
      f16x8 whN = *(const f16x8*)(bh + 131072);
      f16x8 wiR = *(const f16x8*)(bi);
      f16x8 wiZ = *(const f16x8*)(bi + 65536);
      f16x8 wiN = *(const f16x8*)(bi + 131072);
      f32x4 ch[3][2], ci[3][2];
      #pragma unroll
      for (int g = 0; g < 3; ++g) {
        ch[g][0] = (f32x4){0,0,0,0}; ch[g][1] = (f32x4){0,0,0,0};
        ci[g][0] = (f32x4){0,0,0,0}; ci[g][1] = (f32x4){0,0,0,0};
      }
      #pragma unroll
      for (int kk = 0; kk < 8; ++kk) {
        f16x8 nhR, nhZ, nhN, niR, niZ, niN;
        if (kk < 7) {
          nhR = *(const f16x8*)(bh + (kk+1)*32);
          nhZ = *(const f16x8*)(bh + 65536 + (kk+1)*32);
          nhN = *(const f16x8*)(bh + 131072 + (kk+1)*32);
          niR = *(const f16x8*)(bi + (kk+1)*32);
          niZ = *(const f16x8*)(bi + 65536 + (kk+1)*32);
          niN = *(const f16x8*)(bi + 131072 + (kk+1)*32);
        }
        int kc = kk*32 + l4*8;
        f16x8 xH0 = *(const f16x8*)(h1RH + swz(l15, kc));
        f16x8 xL0 = *(const f16x8*)(h1RL + swz(l15, kc));
        f16x8 xH1 = *(const f16x8*)(h1RH + swz(16 + l15, kc));
        f16x8 xL1 = *(const f16x8*)(h1RL + swz(16 + l15, kc));
        f16x8 yH0 = *(const f16x8*)(h0WH + swz(l15, kc));
        f16x8 yL0 = *(const f16x8*)(h0WL + swz(l15, kc));
        f16x8 yH1 = *(const f16x8*)(h0WH + swz(16 + l15, kc));
        f16x8 yL1 = *(const f16x8*)(h0WL + swz(16 + l15, kc));
        ch[0][0] = mfma16(xH0, whR, ch[0][0]); ch[0][0] = mfma16(xL0, whR, ch[0][0]);
        ch[0][1] = mfma16(xH1, whR, ch[0][1]); ch[0][1] = mfma16(xL1, whR, ch[0][1]);
        ch[1][0] = mfma16(xH0, whZ, ch[1][0]); ch[1][0] = mfma16(xL0, whZ, ch[1][0]);
        ch[1][1] = mfma16(xH1, whZ, ch[1][1]); ch[1][1] = mfma16(xL1, whZ, ch[1][1]);
        ch[2][0] = mfma16(xH0, whN, ch[2][0]); ch[2][0] = mfma16(xL0, whN, ch[2][0]);
        ch[2][1] = mfma16(xH1, whN, ch[2][1]); ch[2][1] = mfma16(xL1, whN, ch[2][1]);
        ci[0][0] = mfma16(yH0, wiR, ci[0][0]); ci[0][0] = mfma16(yL0, wiR, ci[0][0]);
        ci[0][1] = mfma16(yH1, wiR, ci[0][1]); ci[0][1] = mfma16(yL1, wiR, ci[0][1]);
        ci[1][0] = mfma16(yH0, wiZ, ci[1][0]); ci[1][0] = mfma16(yL0, wiZ, ci[1][0]);
        ci[1][1] = mfma16(yH1, wiZ, ci[1][1]); ci[1][1] = mfma16(yL1, wiZ, ci[1][1]);
        ci[2][0] = mfma16(yH0, wiN, ci[2][0]); ci[2][0] = mfma16(yL0, wiN, ci[2][0]);
        ci[2][1] = mfma16(yH1, wiN, ci[2][1]); ci[2][1] = mfma16(yL1, wiN, ci[2][1]);
        if (kk < 7) { whR = nhR; whZ = nhZ; whN = nhN; wiR = niR; wiZ = niZ; wiN = niN; }
      }
      int h = ht*16 + l15;
      float biR = bi1L[h], biZ = bi1L[256+h], biN = bi1L[512+h];
      float bhRb = bh1L[h], bhZb = bh1L[256+h], bhNb = bh1L[512+h];
      #pragma unroll
      for (int mt = 0; mt < 2; ++mt) {
        #pragma unroll
        for (int j = 0; j < 4; ++j) {
          int r = mt*16 + l4*4 + j;
          float rg = sigm(ci[0][mt][j] + biR + ch[0][mt][j] + bhRb);
          float zg = sigm(ci[1][mt][j] + biZ + ch[1][mt][j] + bhZb);
          float ng = tanhf(ci[2][mt][j] + biN + rg * (ch[2][mt][j] + bhNb));
          float hold = rdpair(h1RH, h1RL, swz(r, h));
          float hnew = (1.0f - zg) * ng + zg * hold;
          wrsplit(h1WH, h1WL, swz(r, h), hnew);
        }
      }
    }
    __syncthreads();

    // ---- Phase D: qr = h1n @ Wout.T + bout, quantiles, state update
    {
      int r = tid >> 4, li = tid & 15;
      float q0 = 0.0f, q1 = 0.0f, q2 = 0.0f;
      #pragma unroll
      for (int i = 0; i < 16; ++i) {
        int h = li + i*16;
        float v = rdpair(h1WH, h1WL, swz(r, h));
        q0 += v * WoutL[h];
        q1 += v * WoutL[256 + h];
        q2 += v * WoutL[512 + h];
      }
      #pragma unroll
      for (int m = 1; m < 16; m <<= 1) {
        q0 += __shfl_xor(q0, m);
        q1 += __shfl_xor(q1, m);
        q2 += __shfl_xor(q2, m);
      }
      if (li == 0) {
        float qlo = q0 + boutL[0];
        float qm  = qlo + softplusf(q1 + boutL[1] - qlo);
        float qhi = qm  + softplusf(q2 + boutL[2] - qm);
        size_t b = row0 + r;
        out[b*KSTEPS + k]            = qlo;
        out[outP + b*KSTEPS + k]     = qm;
        out[2*outP + b*KSTEPS + k]   = qhi;
        float* sp = sph + r*8;
        float p1 = sp[4], p2 = sp[5];
        sp[0] = qm;
        sp[1] = (qm - p1) * 5.0f;                  // /(2*DT)
        sp[2] = (qm - 2.0f*p2 + p1) * 100.0f;      // /DT^2
        sp[3] = p1; sp[4] = p2; sp[5] = qm;
      }
    }
    __syncthreads();
  }
}

extern "C" void kernel_launch(void* const* d_in, const int* in_sizes, int n_in,
                              void* d_out, int out_size, void* d_ws, size_t ws_size,
                              hipStream_t stream) {
  const float* hf     = (const float*)d_in[0];
  const float* istate = (const float*)d_in[1];
  const float* W1     = (const float*)d_in[2];
  const float* b1     = (const float*)d_in[3];
  const float* W2     = (const float*)d_in[4];
  const float* b2     = (const float*)d_in[5];
  const float* Wih0   = (const float*)d_in[6];
  const float* Whh0   = (const float*)d_in[7];
  const float* bih0   = (const float*)d_in[8];
  const float* bhh0   = (const float*)d_in[9];
  const float* Wih1   = (const float*)d_in[10];
  const float* Whh1   = (const float*)d_in[11];
  const float* bih1   = (const float*)d_in[12];
  const float* bhh1   = (const float*)d_in[13];
  const float* Wout   = (const float*)d_in[14];
  const float* bout   = (const float*)d_in[15];
  float* out = (float*)d_out;
  const int B = in_sizes[0] / HDIM;   // 4096

  char* ws = (char*)d_ws;
  size_t o = 0;
  _Float16* Whh0h  = (_Float16*)(ws + o); o += 393216;
  _Float16* Wih1h  = (_Float16*)(ws + o); o += 393216;
  _Float16* Whh1h  = (_Float16*)(ws + o); o += 393216;
  _Float16* W1h    = (_Float16*)(ws + o); o += 131072;
  _Float16* W1l    = (_Float16*)(ws + o); o += 131072;
  _Float16* W2h    = (_Float16*)(ws + o); o += 262144;
  _Float16* W2l    = (_Float16*)(ws + o); o += 262144;
  _Float16* Wih0hh = (_Float16*)(ws + o); o += 393216;
  _Float16* Wih0hl = (_Float16*)(ws + o); o += 393216;
  _Float16* hfh    = (_Float16*)(ws + o); o += (size_t)B * HDIM * 2;
  _Float16* hfl    = (_Float16*)(ws + o); o += (size_t)B * HDIM * 2;
  float*    teW    = (float*)(ws + o);    o += (size_t)KSTEPS * 768 * 4;
  float*    XcT    = (float*)(ws + o);    o += (size_t)B * 768 * 4;
  if (ws_size < o) return;   // insufficient workspace -> fail loudly (poisoned out)

  const int prep_total = 196608*3 + 65536 + 131072 + 196608 + B*HDIM + KSTEPS*768;
  prep_kernel<<<dim3((prep_total + 255) / 256), dim3(256), 0, stream>>>(
      W1, W2, Wih0, Whh0, Wih1, Whh1, hf,
      Whh0h, Wih1h, Whh1h, W1h, W1l, W2h, W2l, Wih0hh, Wih0hl, hfh, hfl, teW, B);

  xc_kernel<<<dim3(B/16, 12), dim3(64), 0, stream>>>(hfh, hfl, Wih0hh, Wih0hl, bih0, XcT, B);

  hipFuncSetAttribute((const void*)gru_main,
                      hipFuncAttributeMaxDynamicSharedMemorySize, LDS_BYTES);
  gru_main<<<dim3(B/RPB), dim3(NTHR), LDS_BYTES, stream>>>(
      istate, b1, b2, Wih0, bhh0, bih1, bhh1, Wout, bout,
      Whh0h, Wih1h, Whh1h, W1h, W1l, W2h, W2l, hfh, hfl, teW, XcT, out, B);
}

// Round 4
// 3095.902 us; speedup vs baseline: 1.0941x; 1.0941x over previous
//
#include <hip/hip_runtime.h>

#define HDIM 256
#define KSTEPS 30
#define RPB 32            // rows per block
#define NTHR 512          // 8 waves

typedef _Float16 f16x8 __attribute__((ext_vector_type(8)));
typedef float f32x4 __attribute__((ext_vector_type(4)));

__device__ __forceinline__ f32x4 mfma16(f16x8 a, f16x8 b, f32x4 c) {
  return __builtin_amdgcn_mfma_f32_16x16x32_f16(a, b, c, 0, 0, 0);
}

__device__ __forceinline__ float sigm(float x) { return 1.0f / (1.0f + expf(-x)); }
__device__ __forceinline__ float softplusf(float x) {
  return fmaxf(x, 0.0f) + log1pf(expf(-fabsf(x)));
}

// swizzled byte offset for a [32][256] fp16 LDS tile (row stride 512B)
__device__ __forceinline__ int swz(int r, int c) {
  return r * 512 + ((c * 2) ^ ((r & 7) << 4));
}

__device__ __forceinline__ void wrsplit(char* hi, char* lo, int off, float v) {
  _Float16 h = (_Float16)v;
  *(_Float16*)(hi + off) = h;
  *(_Float16*)(lo + off) = (_Float16)(v - (float)h);
}
__device__ __forceinline__ float rdpair(const char* hi, const char* lo, int off) {
  return (float)*(const _Float16*)(hi + off) + (float)*(const _Float16*)(lo + off);
}

// ---------------- prep: f32->fp16 (hi/lo) conversions + teW ----------------
__global__ __launch_bounds__(256) void prep_kernel(
    const float* __restrict__ W1, const float* __restrict__ W2,
    const float* __restrict__ Wih0, const float* __restrict__ Whh0,
    const float* __restrict__ Wih1, const float* __restrict__ Whh1,
    const float* __restrict__ hf,
    _Float16* __restrict__ Whh0h, _Float16* __restrict__ Wih1h,
    _Float16* __restrict__ Whh1h,
    _Float16* __restrict__ W1h, _Float16* __restrict__ W1l,
    _Float16* __restrict__ W2h, _Float16* __restrict__ W2l,
    _Float16* __restrict__ Wih0hh, _Float16* __restrict__ Wih0hl,
    _Float16* __restrict__ hfh, _Float16* __restrict__ hfl,
    float* __restrict__ teW, int B)
{
  int e = blockIdx.x * 256 + threadIdx.x;
  if (e < 196608) { Whh0h[e] = (_Float16)Whh0[e]; return; } e -= 196608;
  if (e < 196608) { Wih1h[e] = (_Float16)Wih1[e]; return; } e -= 196608;
  if (e < 196608) { Whh1h[e] = (_Float16)Whh1[e]; return; } e -= 196608;
  if (e < 65536)  { float x = W1[e]; _Float16 h = (_Float16)x; W1h[e] = h; W1l[e] = (_Float16)(x - (float)h); return; } e -= 65536;
  if (e < 131072) { float x = W2[e]; _Float16 h = (_Float16)x; W2h[e] = h; W2l[e] = (_Float16)(x - (float)h); return; } e -= 131072;
  if (e < 196608) { int n = e >> 8, c = e & 255; float x = Wih0[n*291 + 35 + c]; _Float16 h = (_Float16)x; Wih0hh[e] = h; Wih0hl[e] = (_Float16)(x - (float)h); return; } e -= 196608;
  if (e < B*HDIM) { float x = hf[e]; _Float16 h = (_Float16)x; hfh[e] = h; hfl[e] = (_Float16)(x - (float)h); return; } e -= B*HDIM;
  if (e < KSTEPS*768) {
    int k = e / 768, n = e % 768;
    float pos = (float)k;
    const float fac = -9.210340371976184f / 31.0f;   // -ln(10000)/(TD-1)
    float acc = 0.0f;
    #pragma unroll
    for (int j = 0; j < 31; ++j) {
      int i = j >> 1;
      float ang = pos * expf((float)(2*i) * fac);
      float t = (j & 1) ? cosf(ang) : sinf(ang);
      acc += t * Wih0[n*291 + 3 + j];
    }
    acc += (pos / 30.0f) * Wih0[n*291 + 3 + 31];
    teW[e] = acc;
  }
}

// ------- XcT[n*B + r] = (hf @ Wih0[:,35:291].T)[r,n] + bih0[n]  (transposed, f32) -------
__global__ __launch_bounds__(64) void xc_kernel(
    const _Float16* __restrict__ hfh, const _Float16* __restrict__ hfl,
    const _Float16* __restrict__ Wh, const _Float16* __restrict__ Wl,
    const float* __restrict__ bih0, float* __restrict__ XcT, int B)
{
  int l = threadIdx.x, l15 = l & 15, l4 = l >> 4;
  int bm = blockIdx.x;   // rows bm*16
  int bn = blockIdx.y;   // cols bn*64
  f32x4 acc[4];
  #pragma unroll
  for (int i = 0; i < 4; ++i) acc[i] = (f32x4){0,0,0,0};
  const _Float16* ah = hfh + (size_t)(bm*16 + l15)*256 + l4*8;
  const _Float16* al = hfl + (size_t)(bm*16 + l15)*256 + l4*8;
  #pragma unroll
  for (int kk = 0; kk < 8; ++kk) {
    f16x8 aH = *(const f16x8*)(ah + kk*32);
    f16x8 aL = *(const f16x8*)(al + kk*32);
    #pragma unroll
    for (int i = 0; i < 4; ++i) {
      size_t boff = (size_t)(bn*64 + i*16 + l15)*256 + l4*8 + kk*32;
      f16x8 bH = *(const f16x8*)(Wh + boff);
      f16x8 bL = *(const f16x8*)(Wl + boff);
      acc[i] = mfma16(aH, bH, acc[i]);
      acc[i] = mfma16(aL, bH, acc[i]);
      acc[i] = mfma16(aH, bL, acc[i]);
    }
  }
  #pragma unroll
  for (int i = 0; i < 4; ++i) {
    int n = bn*64 + i*16 + l15;
    float bb = bih0[n];
    #pragma unroll
    for (int j = 0; j < 4; ++j) {
      int r = bm*16 + l4*4 + j;
      XcT[(size_t)n*B + r] = acc[i][j] + bb;
    }
  }
}

// ---------------- main persistent GRU kernel ----------------
// LDS layout (bytes): h tiles are [32][256] fp16 swizzled, 16KB each
#define OFF_H0    0        // buf b: hi @ b*32768, lo @ b*32768+16384
#define OFF_H1    65536    // same structure
#define OFF_WS3   131072   // 768*3 f32 (Wih0[:,0:3])
#define OFF_BHH0  140288   // 768 f32
#define OFF_BI1   143360
#define OFF_BH1   146432
#define OFF_WOUT  149504
#define OFF_SPH   152576   // 32*8 f32
#define OFF_BOUT  153600
#define LDS_BYTES 153616

// LDS=153KB -> 1 block/CU (8 waves = 2 waves/SIMD). Give the allocator the
// full 256-VGPR budget that occupancy makes free; (512,2) launch_bounds
// capped it at 128 and caused ~190MB/dispatch of scratch spill traffic.
__attribute__((amdgpu_waves_per_eu(2, 2)))
__global__ __launch_bounds__(NTHR) void gru_main(
    const float* __restrict__ istate,
    const float* __restrict__ b1g, const float* __restrict__ b2g,
    const float* __restrict__ Wih0, const float* __restrict__ bhh0g,
    const float* __restrict__ bih1g, const float* __restrict__ bhh1g,
    const float* __restrict__ Woutg, const float* __restrict__ boutg,
    const _Float16* __restrict__ Whh0h, const _Float16* __restrict__ Wih1h,
    const _Float16* __restrict__ Whh1h,
    const _Float16* __restrict__ W1h, const _Float16* __restrict__ W1l,
    const _Float16* __restrict__ W2h, const _Float16* __restrict__ W2l,
    const _Float16* __restrict__ hfh, const _Float16* __restrict__ hfl,
    const float* __restrict__ teW, const float* __restrict__ XcT,
    float* __restrict__ out, int B)
{
  extern __shared__ char smem[];
  float* Ws3   = (float*)(smem + OFF_WS3);
  float* bhh0L = (float*)(smem + OFF_BHH0);
  float* bi1L  = (float*)(smem + OFF_BI1);
  float* bh1L  = (float*)(smem + OFF_BH1);
  float* WoutL = (float*)(smem + OFF_WOUT);
  float* sph   = (float*)(smem + OFF_SPH);
  float* boutL = (float*)(smem + OFF_BOUT);

  const int tid = threadIdx.x;
  const int w = tid >> 6;
  const int lane = tid & 63;
  const int l15 = lane & 15;
  const int l4 = lane >> 4;
  const int row0 = blockIdx.x * RPB;

  // ---- constants to LDS
  for (int i = tid; i < 2304; i += NTHR) Ws3[i] = Wih0[(i/3)*291 + (i%3)];
  for (int i = tid; i < 768; i += NTHR) {
    bhh0L[i] = bhh0g[i]; bi1L[i] = bih1g[i]; bh1L[i] = bhh1g[i]; WoutL[i] = Woutg[i];
  }
  if (tid < 3) boutL[tid] = boutg[tid];
  if (tid < RPB) {
    const float* is = istate + (size_t)(row0 + tid) * 3;
    float s0 = is[0], s1 = is[1], s2 = is[2];
    float* sp = sph + tid*8;
    sp[0] = s0; sp[1] = s1; sp[2] = s2;
    sp[3] = s0; sp[4] = s0; sp[5] = s0;   // pos_hist = initial_state[:,0] x3
  }

  // ---- h_init GEMM1: relu(hf @ W1.T + b1) -> hmid in h1-buf1 (hi/lo), 3-pass split
  {
    char* mH = smem + OFF_H1 + 32768;
    char* mL = smem + OFF_H1 + 49152;
    #pragma unroll
    for (int i = 0; i < 2; ++i) {
      int nt = w*2 + i;
      f32x4 acc0 = {0,0,0,0}, acc1 = {0,0,0,0};
      const _Float16* brh = W1h + (nt*16 + l15)*256 + l4*8;
      const _Float16* brl = W1l + (nt*16 + l15)*256 + l4*8;
      const _Float16* a0h = hfh + (size_t)(row0 + l15)*256 + l4*8;
      const _Float16* a0l = hfl + (size_t)(row0 + l15)*256 + l4*8;
      #pragma unroll
      for (int kk = 0; kk < 8; ++kk) {
        f16x8 bH = *(const f16x8*)(brh + kk*32);
        f16x8 bL = *(const f16x8*)(brl + kk*32);
        f16x8 aH0 = *(const f16x8*)(a0h + kk*32);
        f16x8 aL0 = *(const f16x8*)(a0l + kk*32);
        f16x8 aH1 = *(const f16x8*)(a0h + 16*256 + kk*32);
        f16x8 aL1 = *(const f16x8*)(a0l + 16*256 + kk*32);
        acc0 = mfma16(aH0, bH, acc0); acc0 = mfma16(aL0, bH, acc0); acc0 = mfma16(aH0, bL, acc0);
        acc1 = mfma16(aH1, bH, acc1); acc1 = mfma16(aL1, bH, acc1); acc1 = mfma16(aH1, bL, acc1);
      }
      int n = nt*16 + l15;
      float bb = b1g[n];
      #pragma unroll
      for (int mt = 0; mt < 2; ++mt) {
        f32x4 acc = mt ? acc1 : acc0;
        #pragma unroll
        for (int j = 0; j < 4; ++j) {
          int r = mt*16 + l4*4 + j;
          float v = fmaxf(acc[j] + bb, 0.0f);
          wrsplit(mH, mL, swz(r, n), v);
        }
      }
    }
  }
  __syncthreads();

  // ---- h_init GEMM2: tanh(hmid @ W2.T + b2) -> h0 buf0 / h1 buf0 (hi/lo)
  {
    const char* mH = smem + OFF_H1 + 32768;
    const char* mL = smem + OFF_H1 + 49152;
    char* o0H = smem + OFF_H0;          char* o0L = smem + OFF_H0 + 16384;
    char* o1H = smem + OFF_H1;          char* o1L = smem + OFF_H1 + 16384;
    #pragma unroll
    for (int i = 0; i < 4; ++i) {
      int nt = w*4 + i;
      f32x4 acc0 = {0,0,0,0}, acc1 = {0,0,0,0};
      const _Float16* brh = W2h + (nt*16 + l15)*256 + l4*8;
      const _Float16* brl = W2l + (nt*16 + l15)*256 + l4*8;
      #pragma unroll
      for (int kk = 0; kk < 8; ++kk) {
        int kc = kk*32 + l4*8;
        f16x8 bH = *(const f16x8*)(brh + kk*32);
        f16x8 bL = *(const f16x8*)(brl + kk*32);
        f16x8 aH0 = *(const f16x8*)(mH + swz(l15, kc));
        f16x8 aL0 = *(const f16x8*)(mL + swz(l15, kc));
        f16x8 aH1 = *(const f16x8*)(mH + swz(16 + l15, kc));
        f16x8 aL1 = *(const f16x8*)(mL + swz(16 + l15, kc));
        acc0 = mfma16(aH0, bH, acc0); acc0 = mfma16(aL0, bH, acc0); acc0 = mfma16(aH0, bL, acc0);
        acc1 = mfma16(aH1, bH, acc1); acc1 = mfma16(aL1, bH, acc1); acc1 = mfma16(aH1, bL, acc1);
      }
      int n = nt*16 + l15;
      float bb = b2g[n];
      #pragma unroll
      for (int mt = 0; mt < 2; ++mt) {
        f32x4 acc = mt ? acc1 : acc0;
        #pragma unroll
        for (int j = 0; j < 4; ++j) {
          int r = mt*16 + l4*4 + j;
          float v = tanhf(acc[j] + bb);
          if (n < 256) wrsplit(o0H, o0L, swz(r, n), v);
          else         wrsplit(o1H, o1L, swz(r, n - 256), v);
        }
      }
    }
  }
  __syncthreads();

  const size_t outP = (size_t)B * KSTEPS;

  for (int k = 0; k < KSTEPS; ++k) {
    const int rb = (k & 1) * 32768, wb = ((k & 1) ^ 1) * 32768;
    const char* h0RH = smem + OFF_H0 + rb; const char* h0RL = h0RH + 16384;
    char*       h0WH = smem + OFF_H0 + wb; char*       h0WL = h0WH + 16384;
    const char* h1RH = smem + OFF_H1 + rb; const char* h1RL = h1RH + 16384;
    char*       h1WH = smem + OFF_H1 + wb; char*       h1WL = h1WH + 16384;
    const float* teWk = teW + k*768;

    // ---- Phase B: gh0 = h0 @ Whh0.T (pipelined), fused GRU-0 epilogue -> h0W
    #pragma unroll
    for (int hti = 0; hti < 2; ++hti) {
      int ht = w + hti*8;
      int h = ht*16 + l15;
      // hoisted epilogue loads (hide under K-loop)
      float teR = teWk[h], teZ = teWk[256 + h], teN = teWk[512 + h];
      f32x4 xcR[2], xcZ[2], xcN[2];
      #pragma unroll
      for (int mt = 0; mt < 2; ++mt) {
        size_t base = (size_t)row0 + mt*16 + l4*4;
        xcR[mt] = *(const f32x4*)(XcT + (size_t)h*B + base);
        xcZ[mt] = *(const f32x4*)(XcT + (size_t)(256 + h)*B + base);
        xcN[mt] = *(const f32x4*)(XcT + (size_t)(512 + h)*B + base);
      }
      const _Float16* br = Whh0h + (ht*16 + l15)*256 + l4*8;
      f16x8 wR = *(const f16x8*)(br);
      f16x8 wZ = *(const f16x8*)(br + 65536);
      f16x8 wN = *(const f16x8*)(br + 131072);
      f32x4 c[3][2];
      #pragma unroll
      for (int g = 0; g < 3; ++g) { c[g][0] = (f32x4){0,0,0,0}; c[g][1] = (f32x4){0,0,0,0}; }
      #pragma unroll
      for (int kk = 0; kk < 8; ++kk) {
        f16x8 nR, nZ, nN;
        if (kk < 7) {
          nR = *(const f16x8*)(br + (kk+1)*32);
          nZ = *(const f16x8*)(br + 65536 + (kk+1)*32);
          nN = *(const f16x8*)(br + 131072 + (kk+1)*32);
        }
        int kc = kk*32 + l4*8;
        f16x8 aH0 = *(const f16x8*)(h0RH + swz(l15, kc));
        f16x8 aL0 = *(const f16x8*)(h0RL + swz(l15, kc));
        f16x8 aH1 = *(const f16x8*)(h0RH + swz(16 + l15, kc));
        f16x8 aL1 = *(const f16x8*)(h0RL + swz(16 + l15, kc));
        c[0][0] = mfma16(aH0, wR, c[0][0]); c[0][0] = mfma16(aL0, wR, c[0][0]);
        c[0][1] = mfma16(aH1, wR, c[0][1]); c[0][1] = mfma16(aL1, wR, c[0][1]);
        c[1][0] = mfma16(aH0, wZ, c[1][0]); c[1][0] = mfma16(aL0, wZ, c[1][0]);
        c[1][1] = mfma16(aH1, wZ, c[1][1]); c[1][1] = mfma16(aL1, wZ, c[1][1]);
        c[2][0] = mfma16(aH0, wN, c[2][0]); c[2][0] = mfma16(aL0, wN, c[2][0]);
        c[2][1] = mfma16(aH1, wN, c[2][1]); c[2][1] = mfma16(aL1, wN, c[2][1]);
        if (kk < 7) { wR = nR; wZ = nZ; wN = nN; }
      }
      float wR0 = Ws3[h*3+0],       wR1 = Ws3[h*3+1],       wR2 = Ws3[h*3+2];
      float wZ0 = Ws3[(h+256)*3+0], wZ1 = Ws3[(h+256)*3+1], wZ2 = Ws3[(h+256)*3+2];
      float wN0 = Ws3[(h+512)*3+0], wN1 = Ws3[(h+512)*3+1], wN2 = Ws3[(h+512)*3+2];
      float bhR = bhh0L[h], bhZ = bhh0L[256 + h], bhN = bhh0L[512 + h];
      #pragma unroll
      for (int mt = 0; mt < 2; ++mt) {
        #pragma unroll
        for (int j = 0; j < 4; ++j) {
          int r = mt*16 + l4*4 + j;
          const float* sp = sph + r*8;
          float s0 = sp[0], s1 = sp[1], s2 = sp[2];
          float giR = xcR[mt][j] + teR + s0*wR0 + s1*wR1 + s2*wR2;
          float giZ = xcZ[mt][j] + teZ + s0*wZ0 + s1*wZ1 + s2*wZ2;
          float giN = xcN[mt][j] + teN + s0*wN0 + s1*wN1 + s2*wN2;
          float rg = sigm(giR + c[0][mt][j] + bhR);
          float zg = sigm(giZ + c[1][mt][j] + bhZ);
          float ng = tanhf(giN + rg * (c[2][mt][j] + bhN));
          float hold = rdpair(h0RH, h0RL, swz(r, h));
          float hnew = (1.0f - zg) * ng + zg * hold;
          wrsplit(h0WH, h0WL, swz(r, h), hnew);
        }
      }
    }
    __syncthreads();

    // ---- Phase AC (fused): gh1 = h1 @ Whh1.T AND gi1 = h0n @ Wih1.T, GRU-1 epilogue -> h1W
    #pragma unroll
    for (int hti = 0; hti < 2; ++hti) {
      int ht = w + hti*8;
      const _Float16* bh = Whh1h + (ht*16 + l15)*256 + l4*8;
      const _Float16* bi = Wih1h + (ht*16 + l15)*256 + l4*8;
      f16x8 whR = *(const f16x8*)(bh);
      f16x8 whZ = *(const f16x8*)(bh + 65536);
      f16x8 whN = *(const f16x8*)(bh + 131072);
      f16x8 wiR = *(const f16x8*)(bi);
      f16x8 wiZ = *(const f16x8*)(bi + 65536);
      f16x8 wiN = *(const f16x8*)(bi + 131072);
      f32x4 ch[3][2], ci[3][2];
      #pragma unroll
      for (int g = 0; g < 3; ++g) {
        ch[g][0] = (f32x4){0,0,0,0}; ch[g][1] = (f32x4){0,0,0,0};
        ci[g][0] = (f32x4){0,0,0,0}; ci[g][1] = (f32x4){0,0,0,0};
      }
      #pragma unroll
      for (int kk = 0; kk < 8; ++kk) {
        f16x8 nhR, nhZ, nhN, niR, niZ, niN;
        if (kk < 7) {
          nhR = *(const f16x8*)(bh + (kk+1)*32);
          nhZ = *(const f16x8*)(bh + 65536 + (kk+1)*32);
          nhN = *(const f16x8*)(bh + 131072 + (kk+1)*32);
          niR = *(const f16x8*)(bi + (kk+1)*32);
          niZ = *(const f16x8*)(bi + 65536 + (kk+1)*32);
          niN = *(const f16x8*)(bi + 131072 + (kk+1)*32);
        }
        int kc = kk*32 + l4*8;
        f16x8 xH0 = *(const f16x8*)(h1RH + swz(l15, kc));
        f16x8 xL0 = *(const f16x8*)(h1RL + swz(l15, kc));
        f16x8 xH1 = *(const f16x8*)(h1RH + swz(16 + l15, kc));
        f16x8 xL1 = *(const f16x8*)(h1RL + swz(16 + l15, kc));
        f16x8 yH0 = *(const f16x8*)(h0WH + swz(l15, kc));
        f16x8 yL0 = *(const f16x8*)(h0WL + swz(l15, kc));
        f16x8 yH1 = *(const f16x8*)(h0WH + swz(16 + l15, kc));
        f16x8 yL1 = *(const f16x8*)(h0WL + swz(16 + l15, kc));
        ch[0][0] = mfma16(xH0, whR, ch[0][0]); ch[0][0] = mfma16(xL0, whR, ch[0][0]);
        ch[0][1] = mfma16(xH1, whR, ch[0][1]); ch[0][1] = mfma16(xL1, whR, ch[0][1]);
        ch[1][0] = mfma16(xH0, whZ, ch[1][0]); ch[1][0] = mfma16(xL0, whZ, ch[1][0]);
        ch[1][1] = mfma16(xH1, whZ, ch[1][1]); ch[1][1] = mfma16(xL1, whZ, ch[1][1]);
        ch[2][0] = mfma16(xH0, whN, ch[2][0]); ch[2][0] = mfma16(xL0, whN, ch[2][0]);
        ch[2][1] = mfma16(xH1, whN, ch[2][1]); ch[2][1] = mfma16(xL1, whN, ch[2][1]);
        ci[0][0] = mfma16(yH0, wiR, ci[0][0]); ci[0][0] = mfma16(yL0, wiR, ci[0][0]);
        ci[0][1] = mfma16(yH1, wiR, ci[0][1]); ci[0][1] = mfma16(yL1, wiR, ci[0][1]);
        ci[1][0] = mfma16(yH0, wiZ, ci[1][0]); ci[1][0] = mfma16(yL0, wiZ, ci[1][0]);
        ci[1][1] = mfma16(yH1, wiZ, ci[1][1]); ci[1][1] = mfma16(yL1, wiZ, ci[1][1]);
        ci[2][0] = mfma16(yH0, wiN, ci[2][0]); ci[2][0] = mfma16(yL0, wiN, ci[2][0]);
        ci[2][1] = mfma16(yH1, wiN, ci[2][1]); ci[2][1] = mfma16(yL1, wiN, ci[2][1]);
        if (kk < 7) { whR = nhR; whZ = nhZ; whN = nhN; wiR = niR; wiZ = niZ; wiN = niN; }
      }
      int h = ht*16 + l15;
      float biR = bi1L[h], biZ = bi1L[256+h], biN = bi1L[512+h];
      float bhRb = bh1L[h], bhZb = bh1L[256+h], bhNb = bh1L[512+h];
      #pragma unroll
      for (int mt = 0; mt < 2; ++mt) {
        #pragma unroll
        for (int j = 0; j < 4; ++j) {
          int r = mt*16 + l4*4 + j;
          float rg = sigm(ci[0][mt][j] + biR + ch[0][mt][j] + bhRb);
          float zg = sigm(ci[1][mt][j] + biZ + ch[1][mt][j] + bhZb);
          float ng = tanhf(ci[2][mt][j] + biN + rg * (ch[2][mt][j] + bhNb));
          float hold = rdpair(h1RH, h1RL, swz(r, h));
          float hnew = (1.0f - zg) * ng + zg * hold;
          wrsplit(h1WH, h1WL, swz(r, h), hnew);
        }
      }
    }
    __syncthreads();

    // ---- Phase D: qr = h1n @ Wout.T + bout, quantiles, state update
    {
      int r = tid >> 4, li = tid & 15;
      float q0 = 0.0f, q1 = 0.0f, q2 = 0.0f;
      #pragma unroll
      for (int i = 0; i < 16; ++i) {
        int h = li + i*16;
        float v = rdpair(h1WH, h1WL, swz(r, h));
        q0 += v * WoutL[h];
        q1 += v * WoutL[256 + h];
        q2 += v * WoutL[512 + h];
      }
      #pragma unroll
      for (int m = 1; m < 16; m <<= 1) {
        q0 += __shfl_xor(q0, m);
        q1 += __shfl_xor(q1, m);
        q2 += __shfl_xor(q2, m);
      }
      if (li == 0) {
        float qlo = q0 + boutL[0];
        float qm  = qlo + softplusf(q1 + boutL[1] - qlo);
        float qhi = qm  + softplusf(q2 + boutL[2] - qm);
        size_t b = row0 + r;
        out[b*KSTEPS + k]            = qlo;
        out[outP + b*KSTEPS + k]     = qm;
        out[2*outP + b*KSTEPS + k]   = qhi;
        float* sp = sph + r*8;
        float p1 = sp[4], p2 = sp[5];
        sp[0] = qm;
        sp[1] = (qm - p1) * 5.0f;                  // /(2*DT)
        sp[2] = (qm - 2.0f*p2 + p1) * 100.0f;      // /DT^2
        sp[3] = p1; sp[4] = p2; sp[5] = qm;
      }
    }
    __syncthreads();
  }
}

extern "C" void kernel_launch(void* const* d_in, const int* in_sizes, int n_in,
                              void* d_out, int out_size, void* d_ws, size_t ws_size,
                              hipStream_t stream) {
  const float* hf     = (const float*)d_in[0];
  const float* istate = (const float*)d_in[1];
  const float* W1     = (const float*)d_in[2];
  const float* b1     = (const float*)d_in[3];
  const float* W2     = (const float*)d_in[4];
  const float* b2     = (const float*)d_in[5];
  const float* Wih0   = (const float*)d_in[6];
  const float* Whh0   = (const float*)d_in[7];
  const float* bih0   = (const float*)d_in[8];
  const float* bhh0   = (const float*)d_in[9];
  const float* Wih1   = (const float*)d_in[10];
  const float* Whh1   = (const float*)d_in[11];
  const float* bih1   = (const float*)d_in[12];
  const float* bhh1   = (const float*)d_in[13];
  const float* Wout   = (const float*)d_in[14];
  const float* bout   = (const float*)d_in[15];
  float* out = (float*)d_out;
  const int B = in_sizes[0] / HDIM;   // 4096

  char* ws = (char*)d_ws;
  size_t o = 0;
  _Float16* Whh0h  = (_Float16*)(ws + o); o += 393216;
  _Float16* Wih1h  = (_Float16*)(ws + o); o += 393216;
  _Float16* Whh1h  = (_Float16*)(ws + o); o += 393216;
  _Float16* W1h    = (_Float16*)(ws + o); o += 131072;
  _Float16* W1l    = (_Float16*)(ws + o); o += 131072;
  _Float16* W2h    = (_Float16*)(ws + o); o += 262144;
  _Float16* W2l    = (_Float16*)(ws + o); o += 262144;
  _Float16* Wih0hh = (_Float16*)(ws + o); o += 393216;
  _Float16* Wih0hl = (_Float16*)(ws + o); o += 393216;
  _Float16* hfh    = (_Float16*)(ws + o); o += (size_t)B * HDIM * 2;
  _Float16* hfl    = (_Float16*)(ws + o); o += (size_t)B * HDIM * 2;
  float*    teW    = (float*)(ws + o);    o += (size_t)KSTEPS * 768 * 4;
  float*    XcT    = (float*)(ws + o);    o += (size_t)B * 768 * 4;
  if (ws_size < o) return;   // insufficient workspace -> fail loudly (poisoned out)

  const int prep_total = 196608*3 + 65536 + 131072 + 196608 + B*HDIM + KSTEPS*768;
  prep_kernel<<<dim3((prep_total + 255) / 256), dim3(256), 0, stream>>>(
      W1, W2, Wih0, Whh0, Wih1, Whh1, hf,
      Whh0h, Wih1h, Whh1h, W1h, W1l, W2h, W2l, Wih0hh, Wih0hl, hfh, hfl, teW, B);

  xc_kernel<<<dim3(B/16, 12), dim3(64), 0, stream>>>(hfh, hfl, Wih0hh, Wih0hl, bih0, XcT, B);

  hipFuncSetAttribute((const void*)gru_main,
                      hipFuncAttributeMaxDynamicSharedMemorySize, LDS_BYTES);
  gru_main<<<dim3(B/RPB), dim3(NTHR), LDS_BYTES, stream>>>(
      istate, b1, b2, Wih0, bhh0, bih1, bhh1, Wout, bout,
      Whh0h, Wih1h, Whh1h, W1h, W1l, W2h, W2l, hfh, hfl, teW, XcT, out, B);
}